// Round 11
// baseline (929.473 us; speedup 1.0000x reference)
//
#include <hip/hip_runtime.h>
#include <stdint.h>

#define KCODES 8192
#define DIM 256
#define BM 128           // pass1: rows per block; 8 waves: 4 row-groups x 2 col-halves
#define BN 128           // codebook cols per kt tile
#define NTHREADS 512
#define NKT (KCODES / BN)   // 64 tiles
#define NPAIR (NKT * 4)     // 256 pair-steps (2 chunks = 64 d each)

typedef _Float16 h16;
typedef __attribute__((ext_vector_type(8))) _Float16 f16x8;
typedef __attribute__((ext_vector_type(4))) float f32x4;

__device__ __forceinline__ void split8(const float* __restrict__ x, f16x8& h, f16x8& l) {
    #pragma unroll
    for (int i = 0; i < 8; ++i) {
        float v = x[i];
        _Float16 hv = (_Float16)v;          // RNE
        h[i] = hv;
        l[i] = (_Float16)(v - (float)hv);   // exact residual in f32, RNE to f16
    }
}

// ---- ws layout (bytes); total ~5 MB, ws >= 8.4 MB proven since R5 ----
#define WS_C2H   0u          // 8192 f32: 0.5*||c||^2
#define WS_LC    32768u      // 8192 f32: ||rho_c||
#define WS_CN    65536u      // 8192 f32: ||c||
#define WS_CNT   98304u      // 1 int
#define WS_LIST  98560u      // 65536 int
#define WS_CAND  360704u     // 65536 int
#define WS_THR   622848u     // 65536 f32
#define WS_BPH   1048576u    // 4 MB h-only packed image

// ---------------- prep: c2h, lc, cn per code ----------------
__global__ __launch_bounds__(256) void c2x_kernel(const float* __restrict__ cb,
                                                  float* __restrict__ c2h,
                                                  float* __restrict__ lc,
                                                  float* __restrict__ cn, int K) {
    int w = (blockIdx.x * blockDim.x + threadIdx.x) >> 6;
    int lane = threadIdx.x & 63;
    if (w >= K) return;
    const float4 v = *(const float4*)(cb + (size_t)w * DIM + lane * 4);
    float s = 0.f, sr = 0.f;
    const float xs[4] = {v.x, v.y, v.z, v.w};
    #pragma unroll
    for (int i = 0; i < 4; ++i) {
        float x = xs[i];
        s += x * x;
        float hf = (float)(_Float16)x;
        float rho = x - hf;
        sr += rho * rho;
    }
    #pragma unroll
    for (int off = 32; off > 0; off >>= 1) { s += __shfl_down(s, off); sr += __shfl_down(sr, off); }
    if (lane == 0) { c2h[w] = 0.5f * s; cn[w] = sqrtf(s); lc[w] = sqrtf(sr); }
}

// ---------------- pack h-only image ----------------
// 256 pair-blocks of 16 KB. Pair P = kt*4 + (chunk>>1). Within a pair, row
// col has 8 16B slots; logical slot s = (chunk&1)*4 + g holds h of
// d [chunk*32 + g*8 .. +7]; phys = s ^ (col&7). Read addresses are thus
// byte-identical to the R9-proven off_h (chunk even) / off_l (chunk odd).
__global__ __launch_bounds__(256) void pack_h_kernel(const float* __restrict__ cb,
                                                     h16* __restrict__ Bp) {
    const int tid = blockIdx.x * 256 + threadIdx.x;   // 8192*32
    const int code = tid >> 5;
    const int grp = tid & 31;                         // 8-d group
    float x[8];
    *(float4*)&x[0] = *(const float4*)(cb + (size_t)code * DIM + grp * 8);
    *(float4*)&x[4] = *(const float4*)(cb + (size_t)code * DIM + grp * 8 + 4);
    f16x8 hh;
    #pragma unroll
    for (int i = 0; i < 8; ++i) hh[i] = (_Float16)x[i];
    const int kt = code >> 7, col = code & 127;
    const int chunk = grp >> 2, g = grp & 3;
    const int P = kt * 4 + (chunk >> 1);
    const int s = (chunk & 1) * 4 + g;
    const int phys = s ^ (col & 7);
    *(f16x8*)(Bp + (size_t)P * 8192 + col * 64 + phys * 8) = hh;
}

// ---------------- pass 1: hh scores + per-row top-2 of u ----------------
__global__ __launch_bounds__(NTHREADS, 2) void vq_pass1(
    const float* __restrict__ rep, const h16* __restrict__ Bp,
    const float* __restrict__ c2h, const float* __restrict__ lcA,
    const float* __restrict__ cnA, int* __restrict__ cand,
    float* __restrict__ thr) {

    __shared__ __align__(16) h16 ring[3][8192];   // 48 KB

    const int t = threadIdx.x;
    const int lane = t & 63;
    const int c15 = lane & 15;
    const int g = lane >> 4;
    const int w = t >> 6;
    const int wrow = (w >> 1) * 32;
    const int wcol = (w & 1) * 64;
    const int row0 = blockIdx.x * BM;

    // ---- A: h fragments + row norms (hn=||h_r||, rn=||rho_r||) ----
    f16x8 ah[2][8];
    float hn[2], rn[2];
    #pragma unroll
    for (int m = 0; m < 2; ++m) {
        const float* ar = rep + (size_t)(row0 + wrow + m * 16 + c15) * DIM + g * 8;
        float hs = 0.f, rs = 0.f;
        #pragma unroll
        for (int ch = 0; ch < 8; ++ch) {
            float x[8];
            *(float4*)&x[0] = *(const float4*)(ar + ch * 32);
            *(float4*)&x[4] = *(const float4*)(ar + ch * 32 + 4);
            #pragma unroll
            for (int i = 0; i < 8; ++i) {
                _Float16 hv = (_Float16)x[i];
                ah[m][ch][i] = hv;
                float hf = (float)hv;
                hs += hf * hf;
                float rho = x[i] - hf;
                rs += rho * rho;
            }
        }
        hs += __shfl_xor(hs, 16); hs += __shfl_xor(hs, 32);
        rs += __shfl_xor(rs, 16); rs += __shfl_xor(rs, 32);
        hn[m] = sqrtf(hs); rn[m] = sqrtf(rs);
    }

    f32x4 acc[2][4];
    float u1v[2][4], u2v[2][4], B2[2][4];
    int u1i[2][4];
    #pragma unroll
    for (int m = 0; m < 2; ++m)
        #pragma unroll
        for (int n = 0; n < 4; ++n) {
            #pragma unroll
            for (int r = 0; r < 4; ++r) acc[m][n][r] = 0.f;
            u1v[m][n] = -3.4e38f; u2v[m][n] = -3.4e38f; u1i[m][n] = 0;  // [m][r-slot]
        }

    auto issueB = [&](int p2, int slot) {   // stage one 16 KB pair-block
        const h16* src = Bp + (size_t)p2 * 8192 + t * 8;
        h16* dst = &ring[slot][t * 8];
        #pragma unroll
        for (int i = 0; i < 2; ++i)
            __builtin_amdgcn_global_load_lds(
                (const __attribute__((address_space(1))) uint32_t*)(src + i * 4096),
                (__attribute__((address_space(3))) uint32_t*)(dst + i * 4096),
                16, 0, 0);
    };

    asm volatile("s_waitcnt vmcnt(0)" ::: "memory");   // drain A loads
    issueB(0, 0);
    issueB(1, 1);

    int bufq = 0;
    #pragma unroll 1
    for (int kt = 0; kt < NKT; ++kt) {
        const int ktbase = kt * BN;
        #pragma unroll
        for (int pp = 0; pp < 4; ++pp) {
            const int p = kt * 4 + pp;
            if (p == NPAIR - 1) asm volatile("s_waitcnt vmcnt(0) lgkmcnt(0)" ::: "memory");
            else                asm volatile("s_waitcnt vmcnt(2) lgkmcnt(0)" ::: "memory");
            __builtin_amdgcn_s_barrier();
            __builtin_amdgcn_sched_barrier(0);

            if (pp == 0) {   // per-kt: B2[m][n] = bound - c2  (loads before issueB)
                #pragma unroll
                for (int n = 0; n < 4; ++n) {
                    const int col = ktbase + wcol + n * 16 + c15;
                    float cc = c2h[col], lv = lcA[col], cv = cnA[col];
                    #pragma unroll
                    for (int m = 0; m < 2; ++m)
                        B2[m][n] = hn[m] * lv + rn[m] * cv + 0.012f - cc;
                }
            }
            if (p + 2 < NPAIR) {
                int slot = bufq + 2;
                if (slot >= 3) slot -= 3;
                issueB(p + 2, slot);
            }

            const h16* lb = &ring[bufq][0];
            #pragma unroll
            for (int hi = 0; hi < 2; ++hi) {
                const int ch = pp * 2 + hi;          // compile-time chunk 0..7
                #pragma unroll
                for (int n = 0; n < 4; ++n) {
                    const int base = (wcol + n * 16 + c15) * 64;
                    f16x8 bh = *(const f16x8*)&lb[base + (((hi * 4 + g) ^ (lane & 7)) << 3)];
                    #pragma unroll
                    for (int m = 0; m < 2; ++m)
                        acc[m][n] = __builtin_amdgcn_mfma_f32_16x16x32_f16(ah[m][ch], bh, acc[m][n], 0, 0, 0);
                }
            }

            if (pp == 3) {   // per-kt epilogue: u = s1 + bound, track top-2 per (m,r)
                #pragma unroll
                for (int n = 0; n < 4; ++n) {
                    const int col = ktbase + wcol + n * 16 + c15;
                    #pragma unroll
                    for (int m = 0; m < 2; ++m)
                        #pragma unroll
                        for (int r = 0; r < 4; ++r) {
                            float u = acc[m][n][r] + B2[m][n];
                            if (u > u1v[m][r]) { u2v[m][r] = u1v[m][r]; u1v[m][r] = u; u1i[m][r] = col; }
                            else if (u > u2v[m][r]) u2v[m][r] = u;
                            acc[m][n][r] = 0.f;
                        }
                }
            }
            bufq = (bufq + 1 == 3) ? 0 : bufq + 1;
        }
    }

    // ---- merge top-2 across the 16 c15-lanes, then across col-half waves ----
    __syncthreads();   // everyone done reading ring -> ring[0] becomes scratch
    float* sv1 = (float*)&ring[0][0];          // [row][half]
    int* si1 = (int*)((char*)&ring[0][0] + 1024);
    float* sv2 = (float*)((char*)&ring[0][0] + 2048);
    #pragma unroll
    for (int m = 0; m < 2; ++m)
        #pragma unroll
        for (int r = 0; r < 4; ++r) {
            float a1 = u1v[m][r], a2 = u2v[m][r];
            int a1i = u1i[m][r];
            #pragma unroll
            for (int mask = 1; mask <= 8; mask <<= 1) {
                float b1 = __shfl_xor(a1, mask);
                int b1i = __shfl_xor(a1i, mask);
                float b2 = __shfl_xor(a2, mask);
                if (b1 > a1) { a2 = fmaxf(a1, b2); a1 = b1; a1i = b1i; }
                else         { a2 = fmaxf(b1, a2); }
            }
            if (c15 == 0) {
                const int rl = wrow + m * 16 + g * 4 + r;   // 0..127
                sv1[rl * 2 + (w & 1)] = a1;
                si1[rl * 2 + (w & 1)] = a1i;
                sv2[rl * 2 + (w & 1)] = a2;
            }
        }
    __syncthreads();
    if (t < BM) {
        float a1 = sv1[t * 2], a2 = sv2[t * 2];
        int a1i = si1[t * 2];
        float b1 = sv1[t * 2 + 1], b2 = sv2[t * 2 + 1];
        int b1i = si1[t * 2 + 1];
        float u1, u2; int u1idx;
        if (b1 > a1) { u1 = b1; u1idx = b1i; u2 = fmaxf(a1, b2); }
        else         { u1 = a1; u1idx = a1i; u2 = fmaxf(b1, a2); }
        cand[row0 + t] = u1idx;
        thr[row0 + t] = u2;
    }
}

// ---------------- resolve: exact score of candidate; safe iff > thr ----------
__global__ __launch_bounds__(256) void resolve_kernel(
    const float* __restrict__ rep, const float* __restrict__ cb,
    const float* __restrict__ c2h, const int* __restrict__ cand,
    const float* __restrict__ thr, int* __restrict__ out,
    int* __restrict__ cnt, int* __restrict__ list, int N) {
    const int W = (blockIdx.x * 256 + threadIdx.x) >> 6;
    const int lane = threadIdx.x & 63;
    if (W >= N) return;
    const int ci = cand[W];
    const float4 rv = *(const float4*)(rep + (size_t)W * DIM + lane * 4);
    const float4 cv = *(const float4*)(cb + (size_t)ci * DIM + lane * 4);
    float p = rv.x * cv.x + rv.y * cv.y + rv.z * cv.z + rv.w * cv.w;
    #pragma unroll
    for (int off = 32; off > 0; off >>= 1) p += __shfl_down(p, off);
    if (lane == 0) {
        float sex = p - c2h[ci];
        out[W] = ci;                              // provisional (rescan may overwrite)
        if (!(sex > thr[W])) {                    // not provably optimal
            int pos = atomicAdd(cnt, 1);
            list[pos] = W;
        }
    }
}

// ---------------- rescan: proven R4-style 4-pass exact kernel, gathered rows --
__global__ __launch_bounds__(256) void rescan_kernel(
    const float* __restrict__ rep, const float* __restrict__ cb,
    const float* __restrict__ c2h, const int* __restrict__ cnt_p,
    const int* __restrict__ list, int* __restrict__ out) {

    __shared__ __align__(16) h16 lds[2][BN * 64];
    const int cnt = *cnt_p;
    const int t = threadIdx.x;
    const int lane = t & 63;
    const int w = t >> 6;
    const int c15 = lane & 15;
    const int g = lane >> 4;
    const int wrow = w * 16;

    for (int base = blockIdx.x * 64; base < cnt; base += 256 * 64) {
        const int nrows = min(64, cnt - base);
        // ---- A: gathered rows, load + split (4 waves x 16 rows, m=1) ----
        const int aslot = wrow + c15;
        const int grow = list[base + (aslot < nrows ? aslot : 0)];
        f16x8 ah[8], al[8];
        {
            const float* ar = rep + (size_t)grow * DIM + g * 8;
            #pragma unroll
            for (int ch = 0; ch < 8; ++ch) {
                float x[8];
                *(float4*)&x[0] = *(const float4*)(ar + ch * 32);
                *(float4*)&x[4] = *(const float4*)(ar + ch * 32 + 4);
                split8(x, ah[ch], al[ch]);
            }
        }
        f32x4 acc[8];
        float best[4], cc[8];
        int bidx[4];
        #pragma unroll
        for (int n = 0; n < 8; ++n)
            #pragma unroll
            for (int r = 0; r < 4; ++r) acc[n][r] = 0.f;
        #pragma unroll
        for (int r = 0; r < 4; ++r) { best[r] = -3.4e38f; bidx[r] = 0; }

        const int scol = t >> 1;
        const int dslot = t & 1;
        float breg[16];
        auto loadB = [&](int ktbase, int ch) {
            const float* src = cb + (size_t)(ktbase + scol) * DIM + ch * 32 + dslot * 16;
            #pragma unroll
            for (int i = 0; i < 4; ++i) *(float4*)&breg[i * 4] = *(const float4*)(src + i * 4);
        };
        auto writeB = [&](int buf) {
            #pragma unroll
            for (int half = 0; half < 2; ++half) {
                f16x8 hh, ll;
                split8(&breg[half * 8], hh, ll);
                const int s = dslot * 2 + half;
                *(f16x8*)&lds[buf][scol * 64 + ((s ^ (scol & 7)) << 3)] = hh;
                *(f16x8*)&lds[buf][scol * 64 + (((s + 4) ^ (scol & 7)) << 3)] = ll;
            }
        };

        __syncthreads();   // safe re-entry for looped base
        loadB(0, 0);
        writeB(0);
        loadB(0, 1);
        __syncthreads();

        for (int kt = 0; kt < NKT; ++kt) {
            const int ktbase = kt * BN;
            #pragma unroll
            for (int chunk = 0; chunk < 8; ++chunk) {
                const int buf = chunk & 1;
                if (!(chunk == 7 && kt == NKT - 1)) writeB(buf ^ 1);
                if (chunk <= 5) loadB(ktbase, chunk + 2);
                else if (kt + 1 < NKT) loadB(ktbase + BN, chunk - 6);
                if (chunk == 0) {
                    #pragma unroll
                    for (int n = 0; n < 8; ++n) cc[n] = c2h[ktbase + n * 16 + c15];
                }
                #pragma unroll
                for (int n = 0; n < 8; ++n) {
                    const int bb = (n * 16 + c15) * 64;
                    f16x8 bh = *(const f16x8*)&lds[buf][bb + ((g ^ (lane & 7)) << 3)];
                    f16x8 bl = *(const f16x8*)&lds[buf][bb + (((4 + g) ^ (lane & 7)) << 3)];
                    acc[n] = __builtin_amdgcn_mfma_f32_16x16x32_f16(ah[chunk], bh, acc[n], 0, 0, 0);
                    acc[n] = __builtin_amdgcn_mfma_f32_16x16x32_f16(ah[chunk], bl, acc[n], 0, 0, 0);
                    acc[n] = __builtin_amdgcn_mfma_f32_16x16x32_f16(al[chunk], bh, acc[n], 0, 0, 0);
                    acc[n] = __builtin_amdgcn_mfma_f32_16x16x32_f16(al[chunk], bl, acc[n], 0, 0, 0);
                }
                if (chunk == 7) {
                    #pragma unroll
                    for (int n = 0; n < 8; ++n) {
                        const int col = ktbase + n * 16 + c15;
                        #pragma unroll
                        for (int r = 0; r < 4; ++r) {
                            float s2 = acc[n][r] - cc[n];
                            if (s2 > best[r]) { best[r] = s2; bidx[r] = col; }
                            acc[n][r] = 0.f;
                        }
                    }
                }
                __syncthreads();
            }
        }
        #pragma unroll
        for (int r = 0; r < 4; ++r) {
            float bv = best[r];
            int bi = bidx[r];
            #pragma unroll
            for (int mask = 1; mask <= 8; mask <<= 1) {
                float ov = __shfl_xor(bv, mask);
                int oi = __shfl_xor(bi, mask);
                if (ov > bv || (ov == bv && oi < bi)) { bv = ov; bi = oi; }
            }
            const int oslot = wrow + g * 4 + r;
            if (c15 == 0 && oslot < nrows) out[list[base + oslot]] = bi;
        }
    }
}

extern "C" void kernel_launch(void* const* d_in, const int* in_sizes, int n_in,
                              void* d_out, int out_size, void* d_ws, size_t ws_size,
                              hipStream_t stream) {
    const float* rep = (const float*)d_in[0];
    const float* cb = (const float*)d_in[1];
    const int N = in_sizes[0] / DIM;   // 65536
    const int K = in_sizes[1] / DIM;   // 8192
    char* ws = (char*)d_ws;
    float* c2h = (float*)(ws + WS_C2H);
    float* lc  = (float*)(ws + WS_LC);
    float* cn  = (float*)(ws + WS_CN);
    int* cnt   = (int*)(ws + WS_CNT);
    int* list  = (int*)(ws + WS_LIST);
    int* cand  = (int*)(ws + WS_CAND);
    float* thr = (float*)(ws + WS_THR);
    h16* Bph   = (h16*)(ws + WS_BPH);
    int* out = (int*)d_out;

    c2x_kernel<<<dim3((K * 64 + 255) / 256), dim3(256), 0, stream>>>(cb, c2h, lc, cn, K);
    pack_h_kernel<<<dim3(KCODES * 32 / 256), dim3(256), 0, stream>>>(cb, Bph);
    vq_pass1<<<dim3(N / BM), dim3(NTHREADS), 0, stream>>>(rep, Bph, c2h, lc, cn, cand, thr);
    hipMemsetAsync(cnt, 0, sizeof(int), stream);
    resolve_kernel<<<dim3(N / 4), dim3(256), 0, stream>>>(rep, cb, c2h, cand, thr, out, cnt, list, N);
    rescan_kernel<<<dim3(256), dim3(256), 0, stream>>>(rep, cb, c2h, cnt, list, out);
}

// Round 12
// 534.799 us; speedup vs baseline: 1.7380x; 1.7380x over previous
//
#include <hip/hip_runtime.h>
#include <stdint.h>

#define KCODES 8192
#define DIM 256
#define BM 128           // pass1 rows per block; 8 waves: 4 row-groups x 2 col-halves
#define BN 128           // codebook cols per kt tile
#define NTHREADS 512
#define NKT (KCODES / BN)   // 64 tiles
#define NSTEP (NKT * 2)     // 128 steps of 128 d

typedef _Float16 h16;
typedef __attribute__((ext_vector_type(8))) _Float16 f16x8;
typedef __attribute__((ext_vector_type(4))) float f32x4;

__device__ __forceinline__ void split8(const float* __restrict__ x, f16x8& h, f16x8& l) {
    #pragma unroll
    for (int i = 0; i < 8; ++i) {
        float v = x[i];
        _Float16 hv = (_Float16)v;          // RNE
        h[i] = hv;
        l[i] = (_Float16)(v - (float)hv);   // exact residual in f32, RNE to f16
    }
}

__device__ __forceinline__ unsigned int ford(float f) {   // monotone float->uint
    unsigned int b = __float_as_uint(f);
    return (b & 0x80000000u) ? ~b : (b | 0x80000000u);
}

// ---- ws layout (bytes); total 6 MB, ws >= 8.4 MB (proven R5-R11) ----
#define WS_C2H   0u          // 8192 f32
#define WS_LC    32768u      // 8192 f32 ||rho_c||
#define WS_CN    65536u      // 8192 f32 ||c||
#define WS_CNT   98304u      // 1 int
#define WS_LIST  98560u      // 65536 int
#define WS_CAND  360704u     // 65536 int
#define WS_THR   622848u     // 65536 f32
#define WS_KEYS  917504u     // 65536 u64
#define WS_BPH   2097152u    // 4 MB h-only packed image

// ---------------- prep: c2h, lc, cn per code ----------------
__global__ __launch_bounds__(256) void c2x_kernel(const float* __restrict__ cb,
                                                  float* __restrict__ c2h,
                                                  float* __restrict__ lc,
                                                  float* __restrict__ cn, int K) {
    int w = (blockIdx.x * blockDim.x + threadIdx.x) >> 6;
    int lane = threadIdx.x & 63;
    if (w >= K) return;
    const float4 v = *(const float4*)(cb + (size_t)w * DIM + lane * 4);
    float s = 0.f, sr = 0.f;
    const float xs[4] = {v.x, v.y, v.z, v.w};
    #pragma unroll
    for (int i = 0; i < 4; ++i) {
        float x = xs[i];
        s += x * x;
        float hf = (float)(_Float16)x;
        float rho = x - hf;
        sr += rho * rho;
    }
    #pragma unroll
    for (int off = 32; off > 0; off >>= 1) { s += __shfl_down(s, off); sr += __shfl_down(sr, off); }
    if (lane == 0) { c2h[w] = 0.5f * s; cn[w] = sqrtf(s); lc[w] = sqrtf(sr); }
}

// ---------------- pack h-only image (identical layout to R11, proven) --------
__global__ __launch_bounds__(256) void pack_h_kernel(const float* __restrict__ cb,
                                                     h16* __restrict__ Bp) {
    const int tid = blockIdx.x * 256 + threadIdx.x;   // 8192*32
    const int code = tid >> 5;
    const int grp = tid & 31;
    float x[8];
    *(float4*)&x[0] = *(const float4*)(cb + (size_t)code * DIM + grp * 8);
    *(float4*)&x[4] = *(const float4*)(cb + (size_t)code * DIM + grp * 8 + 4);
    f16x8 hh;
    #pragma unroll
    for (int i = 0; i < 8; ++i) hh[i] = (_Float16)x[i];
    const int kt = code >> 7, col = code & 127;
    const int chunk = grp >> 2, g = grp & 3;
    const int P = kt * 4 + (chunk >> 1);
    const int s = (chunk & 1) * 4 + g;
    const int phys = s ^ (col & 7);
    *(f16x8*)(Bp + (size_t)P * 8192 + col * 64 + phys * 8) = hh;
}

// ---------------- pass 1: hh scores + per-row top-2 of upper bound u ---------
// 128 steps x 128 d; double-buffer 2 x 32 KB; 32 MFMA vs 16 ds_read per
// wave-step. vmcnt(0) per step is cheap: loads fly a full step (~3k cyc).
__global__ __launch_bounds__(NTHREADS, 2) void vq_pass1(
    const float* __restrict__ rep, const h16* __restrict__ Bp,
    const float* __restrict__ c2h, const float* __restrict__ lcA,
    const float* __restrict__ cnA, int* __restrict__ cand,
    float* __restrict__ thr) {

    __shared__ __align__(16) h16 dbuf[2][16384];   // 64 KB

    const int t = threadIdx.x;
    const int lane = t & 63;
    const int c15 = lane & 15;
    const int g = lane >> 4;
    const int w = t >> 6;
    const int wrow = (w >> 1) * 32;
    const int wcol = (w & 1) * 64;
    const int row0 = blockIdx.x * BM;

    // ---- A: h fragments + row norms ----
    f16x8 ah[2][8];
    float hn[2], rn[2];
    #pragma unroll
    for (int m = 0; m < 2; ++m) {
        const float* ar = rep + (size_t)(row0 + wrow + m * 16 + c15) * DIM + g * 8;
        float hs = 0.f, rs = 0.f;
        #pragma unroll
        for (int ch = 0; ch < 8; ++ch) {
            float x[8];
            *(float4*)&x[0] = *(const float4*)(ar + ch * 32);
            *(float4*)&x[4] = *(const float4*)(ar + ch * 32 + 4);
            #pragma unroll
            for (int i = 0; i < 8; ++i) {
                _Float16 hv = (_Float16)x[i];
                ah[m][ch][i] = hv;
                float hf = (float)hv;
                hs += hf * hf;
                float rho = x[i] - hf;
                rs += rho * rho;
            }
        }
        hs += __shfl_xor(hs, 16); hs += __shfl_xor(hs, 32);
        rs += __shfl_xor(rs, 16); rs += __shfl_xor(rs, 32);
        hn[m] = sqrtf(hs); rn[m] = sqrtf(rs);
    }

    f32x4 acc[2][4];
    float u1v[2][4], u2v[2][4], B2[2][4];
    int u1i[2][4];
    #pragma unroll
    for (int m = 0; m < 2; ++m)
        #pragma unroll
        for (int n = 0; n < 4; ++n) {
            #pragma unroll
            for (int r = 0; r < 4; ++r) acc[m][n][r] = 0.f;
            u1v[m][n] = -3.4e38f; u2v[m][n] = -3.4e38f; u1i[m][n] = 0;
        }

    auto issueStep = [&](int s2, int b) {   // stage 32 KB (2 pair-blocks)
        const h16* src = Bp + (size_t)s2 * 16384 + t * 8;
        h16* dst = &dbuf[b][t * 8];
        #pragma unroll
        for (int i = 0; i < 4; ++i)
            __builtin_amdgcn_global_load_lds(
                (const __attribute__((address_space(1))) uint32_t*)(src + i * 4096),
                (__attribute__((address_space(3))) uint32_t*)(dst + i * 4096),
                16, 0, 0);
    };

    asm volatile("s_waitcnt vmcnt(0)" ::: "memory");   // drain A loads
    issueStep(0, 0);

    #pragma unroll 1
    for (int kt = 0; kt < NKT; ++kt) {
        const int ktbase = kt * BN;
        #pragma unroll
        for (int q = 0; q < 2; ++q) {       // step s = 2kt+q; buffer = q
            const int s = kt * 2 + q;
            asm volatile("s_waitcnt vmcnt(0) lgkmcnt(0)" ::: "memory");
            __builtin_amdgcn_s_barrier();
            __builtin_amdgcn_sched_barrier(0);

            if (q == 0) {   // per-kt bound constants (before prefetch issue)
                #pragma unroll
                for (int n = 0; n < 4; ++n) {
                    const int col = ktbase + wcol + n * 16 + c15;
                    float cc = c2h[col], lv = lcA[col], cv = cnA[col];
                    #pragma unroll
                    for (int m = 0; m < 2; ++m)
                        B2[m][n] = hn[m] * lv + rn[m] * cv + 0.012f - cc;
                }
            }
            if (s + 1 < NSTEP) issueStep(s + 1, q ^ 1);

            const h16* lb = &dbuf[q][0];
            #pragma unroll
            for (int j = 0; j < 4; ++j) {
                const int ch = q * 4 + j;               // d-chunk 0..7
                const h16* lp = lb + (j >> 1) * 8192;
                #pragma unroll
                for (int n = 0; n < 4; ++n) {
                    const int base = (wcol + n * 16 + c15) * 64;
                    f16x8 bh = *(const f16x8*)&lp[base + ((((j & 1) * 4 + g) ^ (c15 & 7)) << 3)];
                    #pragma unroll
                    for (int m = 0; m < 2; ++m)
                        acc[m][n] = __builtin_amdgcn_mfma_f32_16x16x32_f16(ah[m][ch], bh, acc[m][n], 0, 0, 0);
                }
            }

            if (q == 1) {   // per-kt epilogue: u = s1 + bound; track top-2
                #pragma unroll
                for (int n = 0; n < 4; ++n) {
                    const int col = ktbase + wcol + n * 16 + c15;
                    #pragma unroll
                    for (int m = 0; m < 2; ++m)
                        #pragma unroll
                        for (int r = 0; r < 4; ++r) {
                            float u = acc[m][n][r] + B2[m][n];
                            if (u > u1v[m][r]) { u2v[m][r] = u1v[m][r]; u1v[m][r] = u; u1i[m][r] = col; }
                            else if (u > u2v[m][r]) u2v[m][r] = u;
                            acc[m][n][r] = 0.f;
                        }
                }
            }
        }
    }

    // ---- merge top-2 across 16 c15-lanes, then across col-half waves ----
    __syncthreads();   // all compute done; dbuf[0] becomes scratch
    float* sv1 = (float*)&dbuf[0][0];
    int* si1 = (int*)((char*)&dbuf[0][0] + 1024);
    float* sv2 = (float*)((char*)&dbuf[0][0] + 2048);
    #pragma unroll
    for (int m = 0; m < 2; ++m)
        #pragma unroll
        for (int r = 0; r < 4; ++r) {
            float a1 = u1v[m][r], a2 = u2v[m][r];
            int a1i = u1i[m][r];
            #pragma unroll
            for (int mask = 1; mask <= 8; mask <<= 1) {
                float b1 = __shfl_xor(a1, mask);
                int b1i = __shfl_xor(a1i, mask);
                float b2 = __shfl_xor(a2, mask);
                if (b1 > a1) { a2 = fmaxf(a1, b2); a1 = b1; a1i = b1i; }
                else         { a2 = fmaxf(b1, a2); }
            }
            if (c15 == 0) {
                const int rl = wrow + m * 16 + g * 4 + r;
                sv1[rl * 2 + (w & 1)] = a1;
                si1[rl * 2 + (w & 1)] = a1i;
                sv2[rl * 2 + (w & 1)] = a2;
            }
        }
    __syncthreads();
    if (t < BM) {
        float a1 = sv1[t * 2], a2 = sv2[t * 2];
        int a1i = si1[t * 2];
        float b1 = sv1[t * 2 + 1], b2 = sv2[t * 2 + 1];
        int b1i = si1[t * 2 + 1];
        float u1, u2; int u1idx;
        if (b1 > a1) { u1 = b1; u1idx = b1i; u2 = fmaxf(a1, b2); }
        else         { u1 = a1; u1idx = a1i; u2 = fmaxf(b1, a2); }
        cand[row0 + t] = u1idx;
        thr[row0 + t] = u2;
    }
}

// ---------------- resolve: exact fp32 score of candidate; safe iff > thr -----
__global__ __launch_bounds__(256) void resolve_kernel(
    const float* __restrict__ rep, const float* __restrict__ cb,
    const float* __restrict__ c2h, const int* __restrict__ cand,
    const float* __restrict__ thr, int* __restrict__ out,
    int* __restrict__ cnt, int* __restrict__ list, int N) {
    const int W = (blockIdx.x * 256 + threadIdx.x) >> 6;
    const int lane = threadIdx.x & 63;
    if (W >= N) return;
    const int ci = cand[W];
    const float4 rv = *(const float4*)(rep + (size_t)W * DIM + lane * 4);
    const float4 cv = *(const float4*)(cb + (size_t)ci * DIM + lane * 4);
    float p = rv.x * cv.x + rv.y * cv.y + rv.z * cv.z + rv.w * cv.w;
    #pragma unroll
    for (int off = 32; off > 0; off >>= 1) p += __shfl_down(p, off);
    if (lane == 0) {
        float sex = p - c2h[ci];
        out[W] = ci;                              // provisional
        if (!(sex > thr[W])) {                    // not provably optimal
            int pos = atomicAdd(cnt, 1);
            list[pos] = W;
        }
    }
}

// ---------------- rescan: (row-group x kt) parallel exact 4-pass tiles -------
// Each block: 64 gathered rows x one 128-code tile, R4-proven 4-pass split
// scoring; per-row merge via atomicMax on ordered-float<<32 | ~idx
// (equal score -> larger ~idx -> LOWER idx wins = np argmin tie rule).
__global__ __launch_bounds__(256) void rescan_kernel(
    const float* __restrict__ rep, const float* __restrict__ cb,
    const float* __restrict__ c2h, const int* __restrict__ cnt_p,
    const int* __restrict__ list, unsigned long long* __restrict__ keys) {

    const int cnt = *cnt_p;
    const int base = blockIdx.x * 64;
    if (base >= cnt) return;
    const int nrows = min(64, cnt - base);
    const int ktbase = (int)blockIdx.y * BN;

    __shared__ __align__(16) h16 lds[2][BN * 64];
    const int t = threadIdx.x;
    const int lane = t & 63;
    const int w = t >> 6;
    const int c15 = lane & 15;
    const int g = lane >> 4;
    const int wrow = w * 16;

    // ---- A: gathered rows (4 waves x 16 rows), load + split ----
    const int aslot = wrow + c15;
    const int grow = list[base + (aslot < nrows ? aslot : 0)];
    f16x8 ah[8], al[8];
    {
        const float* ar = rep + (size_t)grow * DIM + g * 8;
        #pragma unroll
        for (int ch = 0; ch < 8; ++ch) {
            float x[8];
            *(float4*)&x[0] = *(const float4*)(ar + ch * 32);
            *(float4*)&x[4] = *(const float4*)(ar + ch * 32 + 4);
            split8(x, ah[ch], al[ch]);
        }
    }
    f32x4 acc[8];
    float cc[8];
    #pragma unroll
    for (int n = 0; n < 8; ++n) {
        #pragma unroll
        for (int r = 0; r < 4; ++r) acc[n][r] = 0.f;
        cc[n] = c2h[ktbase + n * 16 + c15];
    }

    const int scol = t >> 1;
    const int dslot = t & 1;
    float breg[16];
    auto loadB = [&](int ch) {
        const float* src = cb + (size_t)(ktbase + scol) * DIM + ch * 32 + dslot * 16;
        #pragma unroll
        for (int i = 0; i < 4; ++i) *(float4*)&breg[i * 4] = *(const float4*)(src + i * 4);
    };
    auto writeB = [&](int buf) {
        #pragma unroll
        for (int half = 0; half < 2; ++half) {
            f16x8 hh, ll;
            split8(&breg[half * 8], hh, ll);
            const int s = dslot * 2 + half;
            *(f16x8*)&lds[buf][scol * 64 + ((s ^ (scol & 7)) << 3)] = hh;
            *(f16x8*)&lds[buf][scol * 64 + (((s + 4) ^ (scol & 7)) << 3)] = ll;
        }
    };

    loadB(0);
    writeB(0);
    loadB(1);
    __syncthreads();

    #pragma unroll
    for (int chunk = 0; chunk < 8; ++chunk) {
        const int buf = chunk & 1;
        if (chunk != 7) writeB(buf ^ 1);
        if (chunk <= 5) loadB(chunk + 2);
        #pragma unroll
        for (int n = 0; n < 8; ++n) {
            const int bb = (n * 16 + c15) * 64;
            f16x8 bh = *(const f16x8*)&lds[buf][bb + ((g ^ (lane & 7)) << 3)];
            f16x8 bl = *(const f16x8*)&lds[buf][bb + (((4 + g) ^ (lane & 7)) << 3)];
            acc[n] = __builtin_amdgcn_mfma_f32_16x16x32_f16(ah[chunk], bh, acc[n], 0, 0, 0);
            acc[n] = __builtin_amdgcn_mfma_f32_16x16x32_f16(ah[chunk], bl, acc[n], 0, 0, 0);
            acc[n] = __builtin_amdgcn_mfma_f32_16x16x32_f16(al[chunk], bh, acc[n], 0, 0, 0);
            acc[n] = __builtin_amdgcn_mfma_f32_16x16x32_f16(al[chunk], bl, acc[n], 0, 0, 0);
        }
        __syncthreads();
    }

    // per-row best over this tile, tie -> lower col; then atomic merge
    #pragma unroll
    for (int r = 0; r < 4; ++r) {
        float bv = -3.4e38f;
        int bi = 0;
        #pragma unroll
        for (int n = 0; n < 8; ++n) {
            float s2 = acc[n][r] - cc[n];
            const int col = ktbase + n * 16 + c15;
            if (s2 > bv) { bv = s2; bi = col; }
        }
        #pragma unroll
        for (int mask = 1; mask <= 8; mask <<= 1) {
            float ov = __shfl_xor(bv, mask);
            int oi = __shfl_xor(bi, mask);
            if (ov > bv || (ov == bv && oi < bi)) { bv = ov; bi = oi; }
        }
        const int oslot = wrow + g * 4 + r;
        if (c15 == 0 && oslot < nrows) {
            unsigned long long key =
                ((unsigned long long)ford(bv) << 32) | (unsigned int)(~(unsigned int)bi);
            atomicMax(&keys[list[base + oslot]], key);
        }
    }
}

// ---------------- writeback listed rows from merged keys ----------------
__global__ __launch_bounds__(256) void writeback_kernel(
    const int* __restrict__ cnt_p, const int* __restrict__ list,
    const unsigned long long* __restrict__ keys, int* __restrict__ out) {
    int i = blockIdx.x * 256 + threadIdx.x;
    if (i >= *cnt_p) return;
    int row = list[i];
    out[row] = (int)(~(unsigned int)(keys[row] & 0xFFFFFFFFull));
}

extern "C" void kernel_launch(void* const* d_in, const int* in_sizes, int n_in,
                              void* d_out, int out_size, void* d_ws, size_t ws_size,
                              hipStream_t stream) {
    const float* rep = (const float*)d_in[0];
    const float* cb = (const float*)d_in[1];
    const int N = in_sizes[0] / DIM;   // 65536
    const int K = in_sizes[1] / DIM;   // 8192
    char* ws = (char*)d_ws;
    float* c2h = (float*)(ws + WS_C2H);
    float* lc  = (float*)(ws + WS_LC);
    float* cn  = (float*)(ws + WS_CN);
    int* cnt   = (int*)(ws + WS_CNT);
    int* list  = (int*)(ws + WS_LIST);
    int* cand  = (int*)(ws + WS_CAND);
    float* thr = (float*)(ws + WS_THR);
    unsigned long long* keys = (unsigned long long*)(ws + WS_KEYS);
    h16* Bph   = (h16*)(ws + WS_BPH);
    int* out = (int*)d_out;

    c2x_kernel<<<dim3((K * 64 + 255) / 256), dim3(256), 0, stream>>>(cb, c2h, lc, cn, K);
    pack_h_kernel<<<dim3(KCODES * 32 / 256), dim3(256), 0, stream>>>(cb, Bph);
    hipMemsetAsync(cnt, 0, sizeof(int), stream);
    hipMemsetAsync(keys, 0, (size_t)N * sizeof(unsigned long long), stream);
    vq_pass1<<<dim3(N / BM), dim3(NTHREADS), 0, stream>>>(rep, Bph, c2h, lc, cn, cand, thr);
    resolve_kernel<<<dim3(N / 4), dim3(256), 0, stream>>>(rep, cb, c2h, cand, thr, out, cnt, list, N);
    rescan_kernel<<<dim3(N / 64, NKT), dim3(256), 0, stream>>>(rep, cb, c2h, cnt, list, keys);
    writeback_kernel<<<dim3(N / 256), dim3(256), 0, stream>>>(cnt, list, keys, out);
}

// Round 13
// 524.786 us; speedup vs baseline: 1.7711x; 1.0191x over previous
//
#include <hip/hip_runtime.h>
#include <stdint.h>

#define KCODES 8192
#define DIM 256
#define BN 128              // codebook cols per kt tile
#define NKT (KCODES / BN)   // 64 tiles
#define NSTEP (NKT * 4)     // 256 steps of 64 d (one 16 KB pair-block each)

typedef _Float16 h16;
typedef __attribute__((ext_vector_type(8))) _Float16 f16x8;
typedef __attribute__((ext_vector_type(4))) float f32x4;

__device__ __forceinline__ void split8(const float* __restrict__ x, f16x8& h, f16x8& l) {
    #pragma unroll
    for (int i = 0; i < 8; ++i) {
        float v = x[i];
        _Float16 hv = (_Float16)v;          // RNE
        h[i] = hv;
        l[i] = (_Float16)(v - (float)hv);   // exact residual in f32, RNE to f16
    }
}

__device__ __forceinline__ unsigned int ford(float f) {   // monotone float->uint
    unsigned int b = __float_as_uint(f);
    return (b & 0x80000000u) ? ~b : (b | 0x80000000u);
}

// ---- ws layout (bytes); total 6 MB, ws >= 8.4 MB (proven R5-R12) ----
#define WS_C2H   0u
#define WS_LC    32768u
#define WS_CN    65536u
#define WS_CNT   98304u
#define WS_LIST  98560u
#define WS_CAND  360704u
#define WS_THR   622848u
#define WS_KEYS  917504u
#define WS_BPH   2097152u    // 4 MB h-only packed image

// ---------------- prep: c2h, lc, cn per code ----------------
__global__ __launch_bounds__(256) void c2x_kernel(const float* __restrict__ cb,
                                                  float* __restrict__ c2h,
                                                  float* __restrict__ lc,
                                                  float* __restrict__ cn, int K) {
    int w = (blockIdx.x * blockDim.x + threadIdx.x) >> 6;
    int lane = threadIdx.x & 63;
    if (w >= K) return;
    const float4 v = *(const float4*)(cb + (size_t)w * DIM + lane * 4);
    float s = 0.f, sr = 0.f;
    const float xs[4] = {v.x, v.y, v.z, v.w};
    #pragma unroll
    for (int i = 0; i < 4; ++i) {
        float x = xs[i];
        s += x * x;
        float hf = (float)(_Float16)x;
        float rho = x - hf;
        sr += rho * rho;
    }
    #pragma unroll
    for (int off = 32; off > 0; off >>= 1) { s += __shfl_down(s, off); sr += __shfl_down(sr, off); }
    if (lane == 0) { c2h[w] = 0.5f * s; cn[w] = sqrtf(s); lc[w] = sqrtf(sr); }
}

// ---------------- pack h-only image (layout proven R11/R12) ----------------
// 256 pair-blocks of 16 KB; pair P = kt*4 + (chunk>>1); logical slot
// s = (chunk&1)*4 + g holds h of d [chunk*32 + g*8 .. +7]; phys = s ^ (col&7).
__global__ __launch_bounds__(256) void pack_h_kernel(const float* __restrict__ cb,
                                                     h16* __restrict__ Bp) {
    const int tid = blockIdx.x * 256 + threadIdx.x;   // 8192*32
    const int code = tid >> 5;
    const int grp = tid & 31;
    float x[8];
    *(float4*)&x[0] = *(const float4*)(cb + (size_t)code * DIM + grp * 8);
    *(float4*)&x[4] = *(const float4*)(cb + (size_t)code * DIM + grp * 8 + 4);
    f16x8 hh;
    #pragma unroll
    for (int i = 0; i < 8; ++i) hh[i] = (_Float16)x[i];
    const int kt = code >> 7, col = code & 127;
    const int chunk = grp >> 2, g = grp & 3;
    const int P = kt * 4 + (chunk >> 1);
    const int s = (chunk & 1) * 4 + g;
    const int phys = s ^ (col & 7);
    *(f16x8*)(Bp + (size_t)P * 8192 + col * 64 + phys * 8) = hh;
}

// ---------------- pass 1: hh scores + per-row top-2 of upper bound u ---------
// R5-envelope: 256 thr (4 waves), BM=64, wave tile 32x64 (m2 x n4), ring-3
// x 16 KB, counted vmcnt(4). 256 steps of 64 d; per wave-step 8 ds_read_b128
// + 16 MFMA; bound epilogue every 4th step. 3 blocks/CU = 3 independent
// barrier groups overlap each other's rendezvous stalls.
__global__ __launch_bounds__(256, 3) void vq_pass1(
    const float* __restrict__ rep, const h16* __restrict__ Bp,
    const float* __restrict__ c2h, const float* __restrict__ lcA,
    const float* __restrict__ cnA, int* __restrict__ cand,
    float* __restrict__ thr) {

    __shared__ __align__(16) h16 ring[3][8192];   // 48 KB

    const int t = threadIdx.x;
    const int lane = t & 63;
    const int c15 = lane & 15;
    const int g = lane >> 4;
    const int w = t >> 6;                 // wave 0..3
    const int wrow = (w >> 1) * 32;       // row half 0/32
    const int wcol = (w & 1) * 64;        // col half 0/64
    const int row0 = blockIdx.x * 64;

    // ---- A: h fragments + row norms (hn=||h_r||, rn=||rho_r||) ----
    f16x8 ah[2][8];
    float hn[2], rn[2];
    #pragma unroll
    for (int m = 0; m < 2; ++m) {
        const float* ar = rep + (size_t)(row0 + wrow + m * 16 + c15) * DIM + g * 8;
        float hs = 0.f, rs = 0.f;
        #pragma unroll
        for (int ch = 0; ch < 8; ++ch) {
            float x[8];
            *(float4*)&x[0] = *(const float4*)(ar + ch * 32);
            *(float4*)&x[4] = *(const float4*)(ar + ch * 32 + 4);
            #pragma unroll
            for (int i = 0; i < 8; ++i) {
                _Float16 hv = (_Float16)x[i];
                ah[m][ch][i] = hv;
                float hf = (float)hv;
                hs += hf * hf;
                float rho = x[i] - hf;
                rs += rho * rho;
            }
        }
        hs += __shfl_xor(hs, 16); hs += __shfl_xor(hs, 32);
        rs += __shfl_xor(rs, 16); rs += __shfl_xor(rs, 32);
        hn[m] = sqrtf(hs); rn[m] = sqrtf(rs);
    }

    f32x4 acc[2][4];
    float u1v[2][4], u2v[2][4], B2[2][4];
    int u1i[2][4];
    #pragma unroll
    for (int m = 0; m < 2; ++m)
        #pragma unroll
        for (int n = 0; n < 4; ++n) {
            #pragma unroll
            for (int r = 0; r < 4; ++r) acc[m][n][r] = 0.f;
            u1v[m][n] = -3.4e38f; u2v[m][n] = -3.4e38f; u1i[m][n] = 0;
        }

    auto issueStep = [&](int s2, int slot) {   // stage one 16 KB pair-block
        const h16* src = Bp + (size_t)s2 * 8192 + t * 8;
        h16* dst = &ring[slot][t * 8];
        #pragma unroll
        for (int i = 0; i < 4; ++i)
            __builtin_amdgcn_global_load_lds(
                (const __attribute__((address_space(1))) uint32_t*)(src + i * 2048),
                (__attribute__((address_space(3))) uint32_t*)(dst + i * 2048),
                16, 0, 0);
    };

    asm volatile("s_waitcnt vmcnt(0)" ::: "memory");   // drain A loads
    issueStep(0, 0);
    issueStep(1, 1);

    int bufq = 0;
    #pragma unroll 1
    for (int kt = 0; kt < NKT; ++kt) {
        const int ktbase = kt * BN;
        #pragma unroll
        for (int cp = 0; cp < 4; ++cp) {            // step s = kt*4+cp; 64 d
            const int s = kt * 4 + cp;
            // s's 4 loads issued 2 steps ago; newest 4 outstanding are s+1's
            // prefetch -> vmcnt(4) proves s landed (older B2 loads drain too).
            // lgkmcnt(0) drains my ds_reads before the rendezvous.
            if (s == NSTEP - 1) asm volatile("s_waitcnt vmcnt(0) lgkmcnt(0)" ::: "memory");
            else                asm volatile("s_waitcnt vmcnt(4) lgkmcnt(0)" ::: "memory");
            __builtin_amdgcn_s_barrier();
            __builtin_amdgcn_sched_barrier(0);

            // B2 loads BEFORE issueStep so newest-4 vmcnt entries = prefetch
            if (cp == 0) {
                #pragma unroll
                for (int n = 0; n < 4; ++n) {
                    const int col = ktbase + wcol + n * 16 + c15;
                    float cc = c2h[col], lv = lcA[col], cv = cnA[col];
                    #pragma unroll
                    for (int m = 0; m < 2; ++m)
                        B2[m][n] = hn[m] * lv + rn[m] * cv + 0.012f - cc;
                }
            }
            if (s + 2 < NSTEP) {
                int slot = bufq + 2;
                if (slot >= 3) slot -= 3;
                issueStep(s + 2, slot);
            }

            const h16* lb = &ring[bufq][0];
            #pragma unroll
            for (int j = 0; j < 2; ++j) {
                const int ch = cp * 2 + j;          // compile-time d-chunk 0..7
                #pragma unroll
                for (int n = 0; n < 4; ++n) {
                    const int base = (wcol + n * 16 + c15) * 64;
                    f16x8 bh = *(const f16x8*)&lb[base + (((j * 4 + g) ^ (c15 & 7)) << 3)];
                    #pragma unroll
                    for (int m = 0; m < 2; ++m)
                        acc[m][n] = __builtin_amdgcn_mfma_f32_16x16x32_f16(ah[m][ch], bh, acc[m][n], 0, 0, 0);
                }
            }

            if (cp == 3) {   // per-kt epilogue: u = s1 + bound; track top-2
                #pragma unroll
                for (int n = 0; n < 4; ++n) {
                    const int col = ktbase + wcol + n * 16 + c15;
                    #pragma unroll
                    for (int m = 0; m < 2; ++m)
                        #pragma unroll
                        for (int r = 0; r < 4; ++r) {
                            float u = acc[m][n][r] + B2[m][n];
                            if (u > u1v[m][r]) { u2v[m][r] = u1v[m][r]; u1v[m][r] = u; u1i[m][r] = col; }
                            else if (u > u2v[m][r]) u2v[m][r] = u;
                            acc[m][n][r] = 0.f;
                        }
                }
            }
            bufq = (bufq + 1 == 3) ? 0 : bufq + 1;
        }
    }

    // ---- merge top-2 across 16 c15-lanes, then across col-half waves ----
    __syncthreads();   // all compute done; ring[0] becomes scratch
    float* sv1 = (float*)&ring[0][0];          // [row 0..63][half 0..1]
    int* si1 = (int*)((char*)&ring[0][0] + 1024);
    float* sv2 = (float*)((char*)&ring[0][0] + 2048);
    #pragma unroll
    for (int m = 0; m < 2; ++m)
        #pragma unroll
        for (int r = 0; r < 4; ++r) {
            float a1 = u1v[m][r], a2 = u2v[m][r];
            int a1i = u1i[m][r];
            #pragma unroll
            for (int mask = 1; mask <= 8; mask <<= 1) {
                float b1 = __shfl_xor(a1, mask);
                int b1i = __shfl_xor(a1i, mask);
                float b2 = __shfl_xor(a2, mask);
                if (b1 > a1) { a2 = fmaxf(a1, b2); a1 = b1; a1i = b1i; }
                else         { a2 = fmaxf(b1, a2); }
            }
            if (c15 == 0) {
                const int rl = wrow + m * 16 + g * 4 + r;   // 0..63
                sv1[rl * 2 + (w & 1)] = a1;
                si1[rl * 2 + (w & 1)] = a1i;
                sv2[rl * 2 + (w & 1)] = a2;
            }
        }
    __syncthreads();
    if (t < 64) {
        float a1 = sv1[t * 2], a2 = sv2[t * 2];
        int a1i = si1[t * 2];
        float b1 = sv1[t * 2 + 1], b2 = sv2[t * 2 + 1];
        int b1i = si1[t * 2 + 1];
        float u1, u2; int u1idx;
        if (b1 > a1) { u1 = b1; u1idx = b1i; u2 = fmaxf(a1, b2); }
        else         { u1 = a1; u1idx = a1i; u2 = fmaxf(b1, a2); }
        cand[row0 + t] = u1idx;
        thr[row0 + t] = u2;
    }
}

// ---------------- resolve: exact fp32 score of candidate; safe iff > thr -----
__global__ __launch_bounds__(256) void resolve_kernel(
    const float* __restrict__ rep, const float* __restrict__ cb,
    const float* __restrict__ c2h, const int* __restrict__ cand,
    const float* __restrict__ thr, int* __restrict__ out,
    int* __restrict__ cnt, int* __restrict__ list, int N) {
    const int W = (blockIdx.x * 256 + threadIdx.x) >> 6;
    const int lane = threadIdx.x & 63;
    if (W >= N) return;
    const int ci = cand[W];
    const float4 rv = *(const float4*)(rep + (size_t)W * DIM + lane * 4);
    const float4 cv = *(const float4*)(cb + (size_t)ci * DIM + lane * 4);
    float p = rv.x * cv.x + rv.y * cv.y + rv.z * cv.z + rv.w * cv.w;
    #pragma unroll
    for (int off = 32; off > 0; off >>= 1) p += __shfl_down(p, off);
    if (lane == 0) {
        float sex = p - c2h[ci];
        out[W] = ci;                              // provisional
        if (!(sex > thr[W])) {                    // not provably optimal
            int pos = atomicAdd(cnt, 1);
            list[pos] = W;
        }
    }
}

// ---------------- rescan: (row-group x kt) parallel exact 4-pass tiles -------
__global__ __launch_bounds__(256) void rescan_kernel(
    const float* __restrict__ rep, const float* __restrict__ cb,
    const float* __restrict__ c2h, const int* __restrict__ cnt_p,
    const int* __restrict__ list, unsigned long long* __restrict__ keys) {

    const int cnt = *cnt_p;
    const int base = blockIdx.x * 64;
    if (base >= cnt) return;
    const int nrows = min(64, cnt - base);
    const int ktbase = (int)blockIdx.y * BN;

    __shared__ __align__(16) h16 lds[2][BN * 64];
    const int t = threadIdx.x;
    const int lane = t & 63;
    const int w = t >> 6;
    const int c15 = lane & 15;
    const int g = lane >> 4;
    const int wrow = w * 16;

    const int aslot = wrow + c15;
    const int grow = list[base + (aslot < nrows ? aslot : 0)];
    f16x8 ah[8], al[8];
    {
        const float* ar = rep + (size_t)grow * DIM + g * 8;
        #pragma unroll
        for (int ch = 0; ch < 8; ++ch) {
            float x[8];
            *(float4*)&x[0] = *(const float4*)(ar + ch * 32);
            *(float4*)&x[4] = *(const float4*)(ar + ch * 32 + 4);
            split8(x, ah[ch], al[ch]);
        }
    }
    f32x4 acc[8];
    float cc[8];
    #pragma unroll
    for (int n = 0; n < 8; ++n) {
        #pragma unroll
        for (int r = 0; r < 4; ++r) acc[n][r] = 0.f;
        cc[n] = c2h[ktbase + n * 16 + c15];
    }

    const int scol = t >> 1;
    const int dslot = t & 1;
    float breg[16];
    auto loadB = [&](int ch) {
        const float* src = cb + (size_t)(ktbase + scol) * DIM + ch * 32 + dslot * 16;
        #pragma unroll
        for (int i = 0; i < 4; ++i) *(float4*)&breg[i * 4] = *(const float4*)(src + i * 4);
    };
    auto writeB = [&](int buf) {
        #pragma unroll
        for (int half = 0; half < 2; ++half) {
            f16x8 hh, ll;
            split8(&breg[half * 8], hh, ll);
            const int s = dslot * 2 + half;
            *(f16x8*)&lds[buf][scol * 64 + ((s ^ (scol & 7)) << 3)] = hh;
            *(f16x8*)&lds[buf][scol * 64 + (((s + 4) ^ (scol & 7)) << 3)] = ll;
        }
    };

    loadB(0);
    writeB(0);
    loadB(1);
    __syncthreads();

    #pragma unroll
    for (int chunk = 0; chunk < 8; ++chunk) {
        const int buf = chunk & 1;
        if (chunk != 7) writeB(buf ^ 1);
        if (chunk <= 5) loadB(chunk + 2);
        #pragma unroll
        for (int n = 0; n < 8; ++n) {
            const int bb = (n * 16 + c15) * 64;
            f16x8 bh = *(const f16x8*)&lds[buf][bb + ((g ^ (lane & 7)) << 3)];
            f16x8 bl = *(const f16x8*)&lds[buf][bb + (((4 + g) ^ (lane & 7)) << 3)];
            acc[n] = __builtin_amdgcn_mfma_f32_16x16x32_f16(ah[chunk], bh, acc[n], 0, 0, 0);
            acc[n] = __builtin_amdgcn_mfma_f32_16x16x32_f16(ah[chunk], bl, acc[n], 0, 0, 0);
            acc[n] = __builtin_amdgcn_mfma_f32_16x16x32_f16(al[chunk], bh, acc[n], 0, 0, 0);
            acc[n] = __builtin_amdgcn_mfma_f32_16x16x32_f16(al[chunk], bl, acc[n], 0, 0, 0);
        }
        __syncthreads();
    }

    #pragma unroll
    for (int r = 0; r < 4; ++r) {
        float bv = -3.4e38f;
        int bi = 0;
        #pragma unroll
        for (int n = 0; n < 8; ++n) {
            float s2 = acc[n][r] - cc[n];
            const int col = ktbase + n * 16 + c15;
            if (s2 > bv) { bv = s2; bi = col; }
        }
        #pragma unroll
        for (int mask = 1; mask <= 8; mask <<= 1) {
            float ov = __shfl_xor(bv, mask);
            int oi = __shfl_xor(bi, mask);
            if (ov > bv || (ov == bv && oi < bi)) { bv = ov; bi = oi; }
        }
        const int oslot = wrow + g * 4 + r;
        if (c15 == 0 && oslot < nrows) {
            unsigned long long key =
                ((unsigned long long)ford(bv) << 32) | (unsigned int)(~(unsigned int)bi);
            atomicMax(&keys[list[base + oslot]], key);
        }
    }
}

// ---------------- writeback listed rows from merged keys ----------------
__global__ __launch_bounds__(256) void writeback_kernel(
    const int* __restrict__ cnt_p, const int* __restrict__ list,
    const unsigned long long* __restrict__ keys, int* __restrict__ out) {
    int i = blockIdx.x * 256 + threadIdx.x;
    if (i >= *cnt_p) return;
    int row = list[i];
    out[row] = (int)(~(unsigned int)(keys[row] & 0xFFFFFFFFull));
}

extern "C" void kernel_launch(void* const* d_in, const int* in_sizes, int n_in,
                              void* d_out, int out_size, void* d_ws, size_t ws_size,
                              hipStream_t stream) {
    const float* rep = (const float*)d_in[0];
    const float* cb = (const float*)d_in[1];
    const int N = in_sizes[0] / DIM;   // 65536
    const int K = in_sizes[1] / DIM;   // 8192
    char* ws = (char*)d_ws;
    float* c2h = (float*)(ws + WS_C2H);
    float* lc  = (float*)(ws + WS_LC);
    float* cn  = (float*)(ws + WS_CN);
    int* cnt   = (int*)(ws + WS_CNT);
    int* list  = (int*)(ws + WS_LIST);
    int* cand  = (int*)(ws + WS_CAND);
    float* thr = (float*)(ws + WS_THR);
    unsigned long long* keys = (unsigned long long*)(ws + WS_KEYS);
    h16* Bph   = (h16*)(ws + WS_BPH);
    int* out = (int*)d_out;

    c2x_kernel<<<dim3((K * 64 + 255) / 256), dim3(256), 0, stream>>>(cb, c2h, lc, cn, K);
    pack_h_kernel<<<dim3(KCODES * 32 / 256), dim3(256), 0, stream>>>(cb, Bph);
    hipMemsetAsync(cnt, 0, sizeof(int), stream);
    hipMemsetAsync(keys, 0, (size_t)N * sizeof(unsigned long long), stream);
    vq_pass1<<<dim3(N / 64), dim3(256), 0, stream>>>(rep, Bph, c2h, lc, cn, cand, thr);
    resolve_kernel<<<dim3(N / 4), dim3(256), 0, stream>>>(rep, cb, c2h, cand, thr, out, cnt, list, N);
    rescan_kernel<<<dim3(N / 64, NKT), dim3(256), 0, stream>>>(rep, cb, c2h, cnt, list, keys);
    writeback_kernel<<<dim3(N / 256), dim3(256), 0, stream>>>(cnt, list, keys, out);
}